// Round 2
// baseline (823.958 us; speedup 1.0000x reference)
//
#include <hip/hip_runtime.h>
#include <hip/hip_bf16.h>

typedef unsigned int u32;
typedef unsigned long long u64;

#define B 8
#define NANCH 100800
#define NCH 85
#define KPRE 1024
#define MAXDET 100
#define CONF 0.25f
#define IOU_T 0.45f
#define EPS_F 1e-7f
#define MAX_WH 7680.0f
#define CAP 4096
#define NBIN 257
#define BASEBITS 0x3E800000u  // bits of 0.25f

// ---------------- K1: per-anchor score + argmax (wave per anchor) ----------------
// Argmax via max-reduce + equality ballot (ties -> lowest class index, since
// class indices 0..62 live in mask1 which always wins over 63..79 in mask2).
__global__ __launch_bounds__(256) void score_kernel(const float* __restrict__ pred,
                                                    u32* __restrict__ keys,
                                                    unsigned char* __restrict__ cls8,
                                                    u32* __restrict__ ghist,
                                                    u32* __restrict__ gcnt) {
    // zero side buffers consumed by later kernels (kernel-boundary ordering)
    if (blockIdx.x == 0) {
        for (int i = threadIdx.x; i < B * NBIN; i += 256) ghist[i] = 0;
        if (threadIdx.x < B) gcnt[threadIdx.x] = 0;
    }
    const int total = B * NANCH;
    int gtid = blockIdx.x * blockDim.x + threadIdx.x;
    int wid = gtid >> 6;
    int lane = threadIdx.x & 63;
    int nwaves = (gridDim.x * blockDim.x) >> 6;

    for (int a = wid; a < total; a += nwaves) {
        const float* p = pred + (size_t)a * NCH;
        float c1 = p[4 + lane];                       // col4 = obj, cols 5..67 = classes 0..62
        float c2 = (lane < 17) ? p[68 + lane] : 0.0f; // cols 68..84 = classes 63..79
        float obj = __shfl(c1, 0);
        float v1 = (lane >= 1) ? c1 * obj : -1.0f;
        float v2 = (lane < 17) ? c2 * obj : -1.0f;
        float v = fmaxf(v1, v2);
        #pragma unroll
        for (int m = 1; m < 64; m <<= 1) v = fmaxf(v, __shfl_xor(v, m));
        u64 m1 = __ballot(v1 == v);
        u64 m2 = __ballot(v2 == v);
        if (lane == 0) {
            int c = m1 ? (__builtin_ctzll(m1) - 1) : (63 + __builtin_ctzll(m2));
            bool valid = (obj > CONF) && (v > CONF);
            keys[a] = valid ? __float_as_uint(v) : 0u;
            cls8[a] = (unsigned char)c;
        }
    }
}

// ---------------- K2: GPU-wide per-batch histogram ----------------
__global__ __launch_bounds__(256) void hist_kernel(const u32* __restrict__ keys,
                                                   u32* __restrict__ ghist) {
    __shared__ u32 lh[B * NBIN];
    for (int i = threadIdx.x; i < B * NBIN; i += 256) lh[i] = 0;
    __syncthreads();
    int idx = blockIdx.x * 256 + threadIdx.x;
    int stride = gridDim.x * 256;
    for (int i = idx; i < B * NANCH; i += stride) {
        u32 k = keys[i];
        if (k) {
            int b = i / NANCH;
            u32 bin = (k - BASEBITS) >> 16;
            if (bin > 256) bin = 256;
            atomicAdd(&lh[b * NBIN + bin], 1u);
        }
    }
    __syncthreads();
    for (int i = threadIdx.x; i < B * NBIN; i += 256) {
        u32 v = lh[i];
        if (v) atomicAdd(&ghist[i], v);
    }
}

// ---------------- K3: pivot per batch ----------------
__global__ __launch_bounds__(64) void pivot_kernel(const u32* __restrict__ ghist,
                                                   int* __restrict__ gpivot) {
    int b = threadIdx.x;
    if (b < B) {
        int cum = 0, piv = 0;
        for (int t = 256; t >= 0; --t) {
            cum += (int)ghist[b * NBIN + t];
            if (cum >= KPRE) { piv = t; break; }
        }
        gpivot[b] = piv;
    }
}

// ---------------- K4: GPU-wide filter/append ----------------
__global__ __launch_bounds__(256) void filter_kernel(const u32* __restrict__ keys,
                                                     const int* __restrict__ gpivot,
                                                     u32* __restrict__ gcnt,
                                                     u64* __restrict__ cand) {
    int idx = blockIdx.x * 256 + threadIdx.x;
    int stride = gridDim.x * 256;
    for (int i = idx; i < B * NANCH; i += stride) {
        u32 k = keys[i];
        if (k) {
            int b = i / NANCH;
            u32 bin = (k - BASEBITS) >> 16;
            if (bin > 256) bin = 256;
            if ((int)bin >= gpivot[b]) {
                u32 pos = atomicAdd(&gcnt[b], 1u);
                if (pos < CAP)
                    cand[(size_t)b * CAP + pos] = (((u64)(~k)) << 32) | (u32)(i - b * NANCH);
            }
        }
    }
}

// ---------------- K5: per-batch bitonic sort (exact top-1024) + finalize ----------------
__global__ __launch_bounds__(1024) void sort_kernel(const float* __restrict__ pred,
                                                    const unsigned char* __restrict__ cls8,
                                                    const u32* __restrict__ gcnt,
                                                    const u64* __restrict__ cand,
                                                    float* __restrict__ sel_score,
                                                    float* __restrict__ sel_cls,
                                                    float* __restrict__ sel_box,
                                                    float* __restrict__ sel_obox,
                                                    float* __restrict__ sel_area) {
    #pragma clang fp contract(off)
    __shared__ u64 items[CAP];
    const int b = blockIdx.x;
    const int tid = threadIdx.x;
    int n = (int)gcnt[b]; if (n > CAP) n = CAP;
    for (int i = tid; i < CAP; i += 1024)
        items[i] = (i < n) ? cand[(size_t)b * CAP + i] : ~0ull;
    __syncthreads();

    for (int k = 2; k <= CAP; k <<= 1) {
        for (int j = k >> 1; j >= 1; j >>= 1) {
            for (int p = tid; p < CAP / 2; p += 1024) {
                int i = ((p & ~(j - 1)) << 1) | (p & (j - 1));
                int pr = i | j;
                bool up = ((i & k) == 0);
                u64 a = items[i], c = items[pr];
                if ((a > c) == up) { items[i] = c; items[pr] = a; }
            }
            __syncthreads();
        }
    }

    if (tid < KPRE) {
        u64 it = items[tid];
        u32 invk = (u32)(it >> 32);
        int gi = b * KPRE + tid;
        if (invk != 0xFFFFFFFFu && tid < n) {
            u32 k = ~invk;
            u32 idx = (u32)it;
            float score = __uint_as_float(k);
            const float* pb = pred + ((size_t)b * NANCH + idx) * NCH;
            float cx = pb[0], cy = pb[1], w = pb[2], h = pb[3];
            float x1 = cx - w * 0.5f;
            float y1 = cy - h * 0.5f;
            float x2 = cx + w * 0.5f;
            float y2 = cy + h * 0.5f;
            float clsf = (float)cls8[(size_t)b * NANCH + idx];
            float off = clsf * MAX_WH;
            float bx1 = x1 + off, by1 = y1 + off, bx2 = x2 + off, by2 = y2 + off;
            float area = (bx2 - bx1) * (by2 - by1);
            sel_score[gi] = score;
            sel_cls[gi] = clsf;
            ((float4*)sel_box)[gi] = make_float4(x1, y1, x2, y2);
            ((float4*)sel_obox)[gi] = make_float4(bx1, by1, bx2, by2);
            sel_area[gi] = area;
        } else {
            sel_score[gi] = -1.0f;
            sel_cls[gi] = 0.0f;
            ((float4*)sel_box)[gi] = make_float4(0.f, 0.f, 0.f, 0.f);
            ((float4*)sel_obox)[gi] = make_float4(0.f, 0.f, 0.f, 0.f);
            sel_area[gi] = 0.0f;
        }
    }
}

// ---------------- K6: IOU bitmask (upper triangle), words >= row chunk ----------------
__global__ __launch_bounds__(256) void iou_kernel(const float* __restrict__ sel_obox,
                                                  const float* __restrict__ sel_area,
                                                  u64* __restrict__ mask) {
    #pragma clang fp contract(off)
    const int c = blockIdx.x;  // row chunk 0..15
    const int b = blockIdx.y;  // batch
    const int tid = threadIdx.x;
    const int base = c * 64;
    const int ncols = (16 - c) * 64;

    __shared__ float4 sbox[KPRE];
    __shared__ float sarea[KPRE];

    for (int e = tid; e < ncols; e += 256) {
        int j = base + e;
        sbox[e] = ((const float4*)sel_obox)[b * KPRE + j];
        sarea[e] = sel_area[b * KPRE + j];
    }
    __syncthreads();

    const int ntask = 64 * (16 - c);
    for (int task = tid; task < ntask; task += 256) {
        int row = base + (task & 63);
        int w = c + (task >> 6);
        float4 rb = sbox[row - base];
        float ra = sarea[row - base];
        u64 m = 0;
        #pragma unroll 4
        for (int j2 = 0; j2 < 64; ++j2) {
            int jg = w * 64 + j2;
            float4 cb = sbox[jg - base];
            float ca = sarea[jg - base];
            float ltx = fmaxf(rb.x, cb.x);
            float lty = fmaxf(rb.y, cb.y);
            float rbx = fminf(rb.z, cb.z);
            float rby = fminf(rb.w, cb.w);
            float iw = fmaxf(rbx - ltx, 0.0f);
            float ih = fmaxf(rby - lty, 0.0f);
            float inter = iw * ih;
            float uni = ra + ca - inter;
            float iou = inter / (uni + EPS_F);
            if ((iou > IOU_T) && (jg > row)) m |= (1ull << j2);
        }
        mask[((size_t)b * KPRE + row) * 16 + w] = m;
    }
}

// ---------------- K7: sequential greedy resolve + output ----------------
__global__ __launch_bounds__(64) void resolve_kernel(const u64* __restrict__ mask,
                                                     const float* __restrict__ sel_score,
                                                     const float* __restrict__ sel_cls,
                                                     const float* __restrict__ sel_box,
                                                     float* __restrict__ out) {
    const int b = blockIdx.x;
    const int lane = threadIdx.x;

    __shared__ int s_keep[MAXDET];
    __shared__ int s_nk;

    u64 rem = 0; // lane w (<16) owns removed-bits for word w
    for (int w = 0; w < 16; ++w) {
        float s = sel_score[b * KPRE + w * 64 + lane];
        u64 bal = __ballot(s <= 0.0f);
        if (lane == w) rem = bal;
    }

    u64 mykept = 0;          // lane W holds keptbits of word W
    const int q = lane >> 4; // 0..3: quarter of rows this lane accumulates
    const int w16 = lane & 15;

    for (int W = 0; W < 16; ++W) {
        u64 cur = (u64)__shfl((long long)rem, W);
        u64 diag = mask[((size_t)b * KPRE + W * 64 + lane) * 16 + W];
        u64 keptbits = 0;
        for (int t = 0; t < 64; ++t) {
            u64 dm = (u64)__shfl((long long)diag, t);
            if (!((cur >> t) & 1ull)) { keptbits |= (1ull << t); cur |= dm; }
        }
        if (lane == W) { rem = cur; mykept = keptbits; }

        // propagate kept rows' masks to later words: lane (q,w) sums its quarter
        u64 acc = 0;
        if (w16 > W) {
            #pragma unroll
            for (int t0 = 0; t0 < 16; ++t0) {
                int t = q * 16 + t0;
                u64 m = mask[((size_t)b * KPRE + W * 64 + t) * 16 + w16];
                acc |= ((keptbits >> t) & 1ull) ? m : 0ull;
            }
        }
        acc |= (u64)__shfl_xor((long long)acc, 16);
        acc |= (u64)__shfl_xor((long long)acc, 32);
        if (lane < 16 && lane > W) rem |= acc;
    }

    // extract kept indices in order (lane 0 serial, words broadcast by shuffle)
    int nk = 0;
    for (int W = 0; W < 16; ++W) {
        u64 kb = (u64)__shfl((long long)mykept, W);
        if (lane == 0) {
            while (kb && nk < MAXDET) {
                int t = __builtin_ctzll(kb);
                kb &= kb - 1;
                s_keep[nk++] = W * 64 + t;
            }
        }
    }
    if (lane == 0) s_nk = nk;
    __syncthreads();
    nk = s_nk;

    for (int r = lane; r < MAXDET; r += 64) {
        float o0 = 0, o1 = 0, o2 = 0, o3 = 0, o4 = 0, o5 = 0;
        if (r < nk) {
            int i = s_keep[r];
            int gi = b * KPRE + i;
            float4 bx = ((const float4*)sel_box)[gi];
            o0 = bx.x; o1 = bx.y; o2 = bx.z; o3 = bx.w;
            o4 = sel_score[gi];
            o5 = sel_cls[gi];
        }
        float* po = out + ((size_t)b * MAXDET + r) * 6;
        po[0] = o0; po[1] = o1; po[2] = o2; po[3] = o3; po[4] = o4; po[5] = o5;
    }
}

extern "C" void kernel_launch(void* const* d_in, const int* in_sizes, int n_in,
                              void* d_out, int out_size, void* d_ws, size_t ws_size,
                              hipStream_t stream) {
    const float* pred = (const float*)d_in[0];
    float* out = (float*)d_out;
    char* ws = (char*)d_ws;

    // workspace layout (bytes), all 16-aligned
    u32* keys            = (u32*)(ws + 0);                 // 806400*4 = 3225600
    unsigned char* cls8  = (unsigned char*)(ws + 3225600); // 806400  -> 4032000
    u32* ghist           = (u32*)(ws + 4032000);           // 8*257*4 = 8224 -> 4040224
    u32* gcnt            = (u32*)(ws + 4040224);           // 32 -> 4040256
    int* gpivot          = (int*)(ws + 4040256);           // 32 -> 4040288
    u64* cand            = (u64*)(ws + 4040288);           // 8*4096*8 = 262144 -> 4302432
    float* sel_score     = (float*)(ws + 4302432);         // 32768 -> 4335200
    float* sel_cls       = (float*)(ws + 4335200);         // 32768 -> 4367968
    float* sel_box       = (float*)(ws + 4367968);         // 131072 -> 4499040
    float* sel_obox      = (float*)(ws + 4499040);         // 131072 -> 4630112
    float* sel_area      = (float*)(ws + 4630112);         // 32768 -> 4662880
    u64* mask            = (u64*)(ws + 4662880);           // 8*1024*16*8 = 1048576 -> 5711456

    score_kernel<<<4096, 256, 0, stream>>>(pred, keys, cls8, ghist, gcnt);
    hist_kernel<<<64, 256, 0, stream>>>(keys, ghist);
    pivot_kernel<<<1, 64, 0, stream>>>(ghist, gpivot);
    filter_kernel<<<256, 256, 0, stream>>>(keys, gpivot, gcnt, cand);
    sort_kernel<<<B, 1024, 0, stream>>>(pred, cls8, gcnt, cand, sel_score, sel_cls,
                                        sel_box, sel_obox, sel_area);
    iou_kernel<<<dim3(16, B), 256, 0, stream>>>(sel_obox, sel_area, mask);
    resolve_kernel<<<B, 64, 0, stream>>>(mask, sel_score, sel_cls, sel_box, out);
}

// Round 3
// 540.899 us; speedup vs baseline: 1.5233x; 1.5233x over previous
//
#include <hip/hip_runtime.h>
#include <hip/hip_bf16.h>

typedef unsigned int u32;
typedef unsigned long long u64;

#define B 8
#define NANCH 100800
#define NCH 85
#define KPRE 1024
#define MAXDET 100
#define CONF 0.25f
#define IOU_T 0.45f
#define EPS_F 1e-7f
#define MAX_WH 7680.0f
#define CAP 4096
#define NBIN 257
#define BASEBITS 0x3E800000u  // bits of 0.25f
#define NSLICE 32
#define LBUF 1024

// ---------------- K1: per-anchor score + argmax (wave per anchor) ----------------
__global__ __launch_bounds__(256) void score_kernel(const float* __restrict__ pred,
                                                    u32* __restrict__ keys,
                                                    unsigned char* __restrict__ cls8,
                                                    u32* __restrict__ ghist,
                                                    u32* __restrict__ gcnt) {
    // zero side buffers consumed by later kernels (kernel-boundary ordering)
    if (blockIdx.x == 0) {
        for (int i = threadIdx.x; i < B * NBIN; i += 256) ghist[i] = 0;
        if (threadIdx.x < B) gcnt[threadIdx.x] = 0;
    }
    const int total = B * NANCH;
    int gtid = blockIdx.x * blockDim.x + threadIdx.x;
    int wid = gtid >> 6;
    int lane = threadIdx.x & 63;
    int nwaves = (gridDim.x * blockDim.x) >> 6;

    for (int a = wid; a < total; a += nwaves) {
        const float* p = pred + (size_t)a * NCH;
        float c1 = p[4 + lane];                       // col4 = obj, cols 5..67 = classes 0..62
        float c2 = (lane < 17) ? p[68 + lane] : 0.0f; // cols 68..84 = classes 63..79
        float obj = __shfl(c1, 0);
        float v1 = (lane >= 1) ? c1 * obj : -1.0f;
        float v2 = (lane < 17) ? c2 * obj : -1.0f;
        float v = fmaxf(v1, v2);
        #pragma unroll
        for (int m = 1; m < 64; m <<= 1) v = fmaxf(v, __shfl_xor(v, m));
        u64 m1 = __ballot(v1 == v);
        u64 m2 = __ballot(v2 == v);
        if (lane == 0) {
            int c = m1 ? (__builtin_ctzll(m1) - 1) : (63 + __builtin_ctzll(m2));
            bool valid = (obj > CONF) && (v > CONF);
            keys[a] = valid ? __float_as_uint(v) : 0u;
            cls8[a] = (unsigned char)c;
        }
    }
}

// ---------------- K2: GPU-wide per-batch histogram (LDS hist, merge once) ----------------
__global__ __launch_bounds__(256) void hist_kernel(const u32* __restrict__ keys,
                                                   u32* __restrict__ ghist) {
    __shared__ u32 lh[B * NBIN];
    for (int i = threadIdx.x; i < B * NBIN; i += 256) lh[i] = 0;
    __syncthreads();
    int idx = blockIdx.x * 256 + threadIdx.x;
    int stride = gridDim.x * 256;
    for (int i = idx; i < B * NANCH; i += stride) {
        u32 k = keys[i];
        if (k) {
            int b = i / NANCH;
            u32 bin = (k - BASEBITS) >> 16;
            if (bin > 256) bin = 256;
            atomicAdd(&lh[b * NBIN + bin], 1u);
        }
    }
    __syncthreads();
    for (int i = threadIdx.x; i < B * NBIN; i += 256) {
        u32 v = lh[i];
        if (v) atomicAdd(&ghist[i], v);
    }
}

// ---------------- K3: pivot per batch ----------------
__global__ __launch_bounds__(64) void pivot_kernel(const u32* __restrict__ ghist,
                                                   int* __restrict__ gpivot) {
    int b = threadIdx.x;
    if (b < B) {
        int cum = 0, piv = 0;
        for (int t = 256; t >= 0; --t) {
            cum += (int)ghist[b * NBIN + t];
            if (cum >= KPRE) { piv = t; break; }
        }
        gpivot[b] = piv;
    }
}

// ---------------- K4: filter/append, block-aggregated (ONE global atomic per block) ----------------
__global__ __launch_bounds__(256) void filter_kernel(const u32* __restrict__ keys,
                                                     const int* __restrict__ gpivot,
                                                     u32* __restrict__ gcnt,
                                                     u64* __restrict__ cand) {
    const int b = blockIdx.y;
    const int s = blockIdx.x;
    const int SL = (NANCH + NSLICE - 1) / NSLICE;  // 3150
    const int lo = s * SL;
    const int hi = (lo + SL < NANCH) ? lo + SL : NANCH;

    __shared__ u64 buf[LBUF];
    __shared__ int cnt;
    __shared__ u32 sbase;
    if (threadIdx.x == 0) cnt = 0;
    __syncthreads();

    const int piv = gpivot[b];
    const u32* kb = keys + (size_t)b * NANCH;
    for (int i = lo + threadIdx.x; i < hi; i += 256) {
        u32 k = kb[i];
        if (k) {
            u32 bin = (k - BASEBITS) >> 16;
            if (bin > 256) bin = 256;
            if ((int)bin >= piv) {
                int p = atomicAdd(&cnt, 1);
                if (p < LBUF) buf[p] = (((u64)(~k)) << 32) | (u32)i;
            }
        }
    }
    __syncthreads();
    int n = cnt; if (n > LBUF) n = LBUF;
    if (threadIdx.x == 0) sbase = atomicAdd(&gcnt[b], (u32)n);
    __syncthreads();
    u32 base = sbase;
    for (int j = threadIdx.x; j < n; j += 256) {
        u32 pos = base + (u32)j;
        if (pos < CAP) cand[(size_t)b * CAP + pos] = buf[j];
    }
}

// ---------------- K5: per-batch bitonic sort (exact top-1024) + finalize ----------------
__global__ __launch_bounds__(1024) void sort_kernel(const float* __restrict__ pred,
                                                    const unsigned char* __restrict__ cls8,
                                                    const u32* __restrict__ gcnt,
                                                    const u64* __restrict__ cand,
                                                    float* __restrict__ sel_score,
                                                    float* __restrict__ sel_cls,
                                                    float* __restrict__ sel_box,
                                                    float* __restrict__ sel_obox,
                                                    float* __restrict__ sel_area) {
    #pragma clang fp contract(off)
    __shared__ u64 items[CAP];
    const int b = blockIdx.x;
    const int tid = threadIdx.x;
    int n = (int)gcnt[b]; if (n > CAP) n = CAP;
    for (int i = tid; i < CAP; i += 1024)
        items[i] = (i < n) ? cand[(size_t)b * CAP + i] : ~0ull;
    __syncthreads();

    for (int k = 2; k <= CAP; k <<= 1) {
        for (int j = k >> 1; j >= 1; j >>= 1) {
            for (int p = tid; p < CAP / 2; p += 1024) {
                int i = ((p & ~(j - 1)) << 1) | (p & (j - 1));
                int pr = i | j;
                bool up = ((i & k) == 0);
                u64 a = items[i], c = items[pr];
                if ((a > c) == up) { items[i] = c; items[pr] = a; }
            }
            __syncthreads();
        }
    }

    if (tid < KPRE) {
        u64 it = items[tid];
        u32 invk = (u32)(it >> 32);
        int gi = b * KPRE + tid;
        if (invk != 0xFFFFFFFFu && tid < n) {
            u32 k = ~invk;
            u32 idx = (u32)it;
            float score = __uint_as_float(k);
            const float* pb = pred + ((size_t)b * NANCH + idx) * NCH;
            float cx = pb[0], cy = pb[1], w = pb[2], h = pb[3];
            float x1 = cx - w * 0.5f;
            float y1 = cy - h * 0.5f;
            float x2 = cx + w * 0.5f;
            float y2 = cy + h * 0.5f;
            float clsf = (float)cls8[(size_t)b * NANCH + idx];
            float off = clsf * MAX_WH;
            float bx1 = x1 + off, by1 = y1 + off, bx2 = x2 + off, by2 = y2 + off;
            float area = (bx2 - bx1) * (by2 - by1);
            sel_score[gi] = score;
            sel_cls[gi] = clsf;
            ((float4*)sel_box)[gi] = make_float4(x1, y1, x2, y2);
            ((float4*)sel_obox)[gi] = make_float4(bx1, by1, bx2, by2);
            sel_area[gi] = area;
        } else {
            sel_score[gi] = -1.0f;
            sel_cls[gi] = 0.0f;
            ((float4*)sel_box)[gi] = make_float4(0.f, 0.f, 0.f, 0.f);
            ((float4*)sel_obox)[gi] = make_float4(0.f, 0.f, 0.f, 0.f);
            sel_area[gi] = 0.0f;
        }
    }
}

// ---------------- K6: IOU bitmask (upper triangle), words >= row chunk ----------------
__global__ __launch_bounds__(256) void iou_kernel(const float* __restrict__ sel_obox,
                                                  const float* __restrict__ sel_area,
                                                  u64* __restrict__ mask) {
    #pragma clang fp contract(off)
    const int c = blockIdx.x;  // row chunk 0..15
    const int b = blockIdx.y;  // batch
    const int tid = threadIdx.x;
    const int base = c * 64;
    const int ncols = (16 - c) * 64;

    __shared__ float4 sbox[KPRE];
    __shared__ float sarea[KPRE];

    for (int e = tid; e < ncols; e += 256) {
        int j = base + e;
        sbox[e] = ((const float4*)sel_obox)[b * KPRE + j];
        sarea[e] = sel_area[b * KPRE + j];
    }
    __syncthreads();

    const int ntask = 64 * (16 - c);
    for (int task = tid; task < ntask; task += 256) {
        int row = base + (task & 63);
        int w = c + (task >> 6);
        float4 rb = sbox[row - base];
        float ra = sarea[row - base];
        u64 m = 0;
        #pragma unroll 4
        for (int j2 = 0; j2 < 64; ++j2) {
            int jg = w * 64 + j2;
            float4 cb = sbox[jg - base];
            float ca = sarea[jg - base];
            float ltx = fmaxf(rb.x, cb.x);
            float lty = fmaxf(rb.y, cb.y);
            float rbx = fminf(rb.z, cb.z);
            float rby = fminf(rb.w, cb.w);
            float iw = fmaxf(rbx - ltx, 0.0f);
            float ih = fmaxf(rby - lty, 0.0f);
            float inter = iw * ih;
            float uni = ra + ca - inter;
            float iou = inter / (uni + EPS_F);
            if ((iou > IOU_T) && (jg > row)) m |= (1ull << j2);
        }
        mask[((size_t)b * KPRE + row) * 16 + w] = m;
    }
}

// ---------------- K7: sequential greedy resolve + output ----------------
__global__ __launch_bounds__(64) void resolve_kernel(const u64* __restrict__ mask,
                                                     const float* __restrict__ sel_score,
                                                     const float* __restrict__ sel_cls,
                                                     const float* __restrict__ sel_box,
                                                     float* __restrict__ out) {
    const int b = blockIdx.x;
    const int lane = threadIdx.x;

    __shared__ int s_keep[MAXDET];
    __shared__ int s_nk;

    u64 rem = 0; // lane w (<16) owns removed-bits for word w
    for (int w = 0; w < 16; ++w) {
        float s = sel_score[b * KPRE + w * 64 + lane];
        u64 bal = __ballot(s <= 0.0f);
        if (lane == w) rem = bal;
    }

    u64 mykept = 0;          // lane W holds keptbits of word W
    const int q = lane >> 4; // 0..3: quarter of rows this lane accumulates
    const int w16 = lane & 15;

    for (int W = 0; W < 16; ++W) {
        u64 cur = (u64)__shfl((long long)rem, W);
        u64 diag = mask[((size_t)b * KPRE + W * 64 + lane) * 16 + W];
        u64 keptbits = 0;
        for (int t = 0; t < 64; ++t) {
            u64 dm = (u64)__shfl((long long)diag, t);
            if (!((cur >> t) & 1ull)) { keptbits |= (1ull << t); cur |= dm; }
        }
        if (lane == W) { rem = cur; mykept = keptbits; }

        // propagate kept rows' masks to later words: lane (q,w) sums its quarter
        u64 acc = 0;
        if (w16 > W) {
            #pragma unroll
            for (int t0 = 0; t0 < 16; ++t0) {
                int t = q * 16 + t0;
                u64 m = mask[((size_t)b * KPRE + W * 64 + t) * 16 + w16];
                acc |= ((keptbits >> t) & 1ull) ? m : 0ull;
            }
        }
        acc |= (u64)__shfl_xor((long long)acc, 16);
        acc |= (u64)__shfl_xor((long long)acc, 32);
        if (lane < 16 && lane > W) rem |= acc;
    }

    // extract kept indices in order
    int nk = 0;
    for (int W = 0; W < 16; ++W) {
        u64 kb = (u64)__shfl((long long)mykept, W);
        if (lane == 0) {
            while (kb && nk < MAXDET) {
                int t = __builtin_ctzll(kb);
                kb &= kb - 1;
                s_keep[nk++] = W * 64 + t;
            }
        }
    }
    if (lane == 0) s_nk = nk;
    __syncthreads();
    nk = s_nk;

    for (int r = lane; r < MAXDET; r += 64) {
        float o0 = 0, o1 = 0, o2 = 0, o3 = 0, o4 = 0, o5 = 0;
        if (r < nk) {
            int i = s_keep[r];
            int gi = b * KPRE + i;
            float4 bx = ((const float4*)sel_box)[gi];
            o0 = bx.x; o1 = bx.y; o2 = bx.z; o3 = bx.w;
            o4 = sel_score[gi];
            o5 = sel_cls[gi];
        }
        float* po = out + ((size_t)b * MAXDET + r) * 6;
        po[0] = o0; po[1] = o1; po[2] = o2; po[3] = o3; po[4] = o4; po[5] = o5;
    }
}

extern "C" void kernel_launch(void* const* d_in, const int* in_sizes, int n_in,
                              void* d_out, int out_size, void* d_ws, size_t ws_size,
                              hipStream_t stream) {
    const float* pred = (const float*)d_in[0];
    float* out = (float*)d_out;
    char* ws = (char*)d_ws;

    // workspace layout (bytes), all 16-aligned
    u32* keys            = (u32*)(ws + 0);                 // 806400*4 = 3225600
    unsigned char* cls8  = (unsigned char*)(ws + 3225600); // 806400  -> 4032000
    u32* ghist           = (u32*)(ws + 4032000);           // 8*257*4 = 8224 -> 4040224
    u32* gcnt            = (u32*)(ws + 4040224);           // 32 -> 4040256
    int* gpivot          = (int*)(ws + 4040256);           // 32 -> 4040288
    u64* cand            = (u64*)(ws + 4040288);           // 8*4096*8 = 262144 -> 4302432
    float* sel_score     = (float*)(ws + 4302432);         // 32768 -> 4335200
    float* sel_cls       = (float*)(ws + 4335200);         // 32768 -> 4367968
    float* sel_box       = (float*)(ws + 4367968);         // 131072 -> 4499040
    float* sel_obox      = (float*)(ws + 4499040);         // 131072 -> 4630112
    float* sel_area      = (float*)(ws + 4630112);         // 32768 -> 4662880
    u64* mask            = (u64*)(ws + 4662880);           // 8*1024*16*8 = 1048576 -> 5711456

    score_kernel<<<4096, 256, 0, stream>>>(pred, keys, cls8, ghist, gcnt);
    hist_kernel<<<64, 256, 0, stream>>>(keys, ghist);
    pivot_kernel<<<1, 64, 0, stream>>>(ghist, gpivot);
    filter_kernel<<<dim3(NSLICE, B), 256, 0, stream>>>(keys, gpivot, gcnt, cand);
    sort_kernel<<<B, 1024, 0, stream>>>(pred, cls8, gcnt, cand, sel_score, sel_cls,
                                        sel_box, sel_obox, sel_area);
    iou_kernel<<<dim3(16, B), 256, 0, stream>>>(sel_obox, sel_area, mask);
    resolve_kernel<<<B, 64, 0, stream>>>(mask, sel_score, sel_cls, sel_box, out);
}